// Round 3
// baseline (852.697 us; speedup 1.0000x reference)
//
#include <hip/hip_runtime.h>
#include <math.h>

typedef unsigned short u16;
typedef unsigned int   u32;
typedef __attribute__((ext_vector_type(8))) short bf16x8;          // 8 bf16 = 4 VGPR (MFMA A/B frag)
typedef __attribute__((ext_vector_type(4))) float f32x4;           // MFMA C/D frag
typedef __attribute__((ext_vector_type(4))) unsigned short u16x4;

__device__ __forceinline__ float bf2f(u16 v){ return __uint_as_float(((u32)v) << 16); }
__device__ __forceinline__ u16 f2bf(float f){
  u32 u = __float_as_uint(f);
  return (u16)((u + 0x7fffu + ((u >> 16) & 1u)) >> 16);  // RNE
}
__device__ __forceinline__ float elu1(float x){ return x > 0.f ? x + 1.f : __expf(x); }
__device__ __forceinline__ float gelu_f(float v){
  float u = 0.7978845608f * (v + 0.044715f * v * v * v);
  float e = __expf(-2.f * fabsf(u));
  float th = copysignf((1.f - e) / (1.f + e), u);
  return 0.5f * v * (1.f + th);
}

// ---------------- cast f32 -> bf16, vectorized x4 ----------------
__global__ __launch_bounds__(256) void k_cast(const float* __restrict__ src, u16* __restrict__ dst, int n4){
  int i = blockIdx.x * 256 + threadIdx.x;
  int stride = gridDim.x * 256;
  for (; i < n4; i += stride){
    float4 v = ((const float4*)src)[i];
    u16x4 o; o.x = f2bf(v.x); o.y = f2bf(v.y); o.z = f2bf(v.z); o.w = f2bf(v.w);
    ((u16x4*)dst)[i] = o;
  }
}

// concat q_b,k_b,v_b -> one 3072-float bias
__global__ void k_cat3(const float* __restrict__ a, const float* __restrict__ b,
                       const float* __restrict__ c, float* __restrict__ dst){
  int i = blockIdx.x * 256 + threadIdx.x;
  dst[i] = i < 1024 ? a[i] : (i < 2048 ? b[i - 1024] : c[i - 2048]);
}

// ---------------- LayerNorm over C=1024: f32 in -> bf16 out ----------------
__global__ __launch_bounds__(256) void k_ln(const float* __restrict__ x, const float* __restrict__ w,
                                            const float* __restrict__ b, u16* __restrict__ out){
  const int t = threadIdx.x;
  const size_t m = blockIdx.x;
  float4 v = ((const float4*)(x + m * 1024))[t];
  float s  = v.x + v.y + v.z + v.w;
  float s2 = v.x*v.x + v.y*v.y + v.z*v.z + v.w*v.w;
  #pragma unroll
  for (int o = 32; o > 0; o >>= 1){ s += __shfl_down(s, o, 64); s2 += __shfl_down(s2, o, 64); }
  __shared__ float red[8];
  if ((t & 63) == 0){ red[t >> 6] = s; red[4 + (t >> 6)] = s2; }
  __syncthreads();
  s  = red[0] + red[1] + red[2] + red[3];
  s2 = red[4] + red[5] + red[6] + red[7];
  float mu  = s * (1.f / 1024.f);
  float inv = rsqrtf(s2 * (1.f / 1024.f) - mu * mu + 1e-5f);
  float4 wv = ((const float4*)w)[t];
  float4 bv = ((const float4*)b)[t];
  u16x4 o;
  o.x = f2bf((v.x - mu) * inv * wv.x + bv.x);
  o.y = f2bf((v.y - mu) * inv * wv.y + bv.y);
  o.z = f2bf((v.z - mu) * inv * wv.z + bv.z);
  o.w = f2bf((v.w - mu) * inv * wv.w + bv.w);
  ((u16x4*)(out + m * 1024))[t] = o;
}

// ---------------- per-token linear attention ----------------
__global__ __launch_bounds__(256) void k_attn(const u16* __restrict__ qkv, u16* __restrict__ out){
  __shared__ float qe[4][16][68];
  __shared__ float ke[4][16][68];
  __shared__ float sm[4][16][20];
  const int w = threadIdx.x >> 6, lane = threadIdx.x & 63;
  const size_t m = (size_t)blockIdx.x * 4 + w;
  const u16* base = qkv + m * 3072;
  #pragma unroll
  for (int i = 0; i < 8; ++i){
    int idx = i * 64 + lane;
    int h = idx >> 5, c2 = (idx & 31) * 2;
    u32 qv = ((const u32*)base)[idx];
    u32 kv = ((const u32*)base)[512 + idx];
    float2 qf, kf;
    qf.x = elu1(bf2f((u16)(qv & 0xffffu))); qf.y = elu1(bf2f((u16)(qv >> 16)));
    kf.x = elu1(bf2f((u16)(kv & 0xffffu))); kf.y = elu1(bf2f((u16)(kv >> 16)));
    *(float2*)&qe[w][h][c2] = qf;
    *(float2*)&ke[w][h][c2] = kf;
  }
  float vr[16];
  #pragma unroll
  for (int h = 0; h < 16; ++h) vr[h] = bf2f(base[2048 + h * 64 + lane]);
  __syncthreads();
  const int sh = lane >> 2, jb = lane & 3;
  float sacc[4] = {0.f, 0.f, 0.f, 0.f};
  #pragma unroll
  for (int d4 = 0; d4 < 16; ++d4){
    float4 q4 = *(const float4*)&qe[w][sh][d4 * 4];
    #pragma unroll
    for (int j = 0; j < 4; ++j){
      float4 k4 = *(const float4*)&ke[w][4 * jb + j][d4 * 4];
      sacc[j] += q4.x*k4.x + q4.y*k4.y + q4.z*k4.z + q4.w*k4.w;
    }
  }
  #pragma unroll
  for (int j = 0; j < 4; ++j) sm[w][sh][4 * jb + j] = sacc[j];
  float part = sacc[0] + sacc[1] + sacc[2] + sacc[3];
  part += __shfl_xor(part, 1, 64);
  part += __shfl_xor(part, 2, 64);
  if (jb == 0) sm[w][sh][16] = part;
  __syncthreads();
  float acc[16];
  #pragma unroll
  for (int h = 0; h < 16; ++h) acc[h] = 0.f;
  #pragma unroll
  for (int h = 0; h < 16; ++h){
    #pragma unroll
    for (int j4 = 0; j4 < 4; ++j4){
      float4 s4 = *(const float4*)&sm[w][h][j4 * 4];
      acc[h] += s4.x*vr[4*j4] + s4.y*vr[4*j4+1] + s4.z*vr[4*j4+2] + s4.w*vr[4*j4+3];
    }
  }
  u16* ob = out + m * 1024;
  #pragma unroll
  for (int h = 0; h < 16; ++h)
    ob[h * 64 + lane] = f2bf(acc[h] / sm[w][h][16]);
}

// ---------------- 256x256-tile 8-wave bf16 GEMM ----------------
// Quad-ahead pipelined schedule, 2 barriers per K-tile, counted vmcnt.
// C = A(M,K) * W(N,K)^T + bias.  EPI 0: bf16 out  1: f32 = res + v  2: bf16 = gelu(v)  3: f32 += v
template<int Q>
__device__ __forceinline__ void quadf(f32x4 (&acc)[8][4], const bf16x8 (&a)[2][2], const bf16x8 (&b)[4][2]){
  __builtin_amdgcn_s_setprio(1);
  #pragma unroll
  for (int s = 0; s < 2; ++s)
    #pragma unroll
    for (int i = 0; i < 2; ++i)
      #pragma unroll
      for (int nf = 0; nf < 4; ++nf)
        acc[2*Q+i][nf] = __builtin_amdgcn_mfma_f32_16x16x32_bf16(a[i][s], b[nf][s], acc[2*Q+i][nf], 0, 0, 0);
  __builtin_amdgcn_s_setprio(0);
}

template<int EPI>
__global__ __launch_bounds__(512, 2) void k_gemm(const u16* __restrict__ A, const u16* __restrict__ W,
                                                 const float* __restrict__ bias, const float* __restrict__ res,
                                                 void* __restrict__ outp, int N, int K, int nbn){
  __shared__ alignas(16) char lds[131072];   // buf b: A @ b*65536 (32K), B @ b*65536+32768 (32K)
  const int tid  = threadIdx.x;
  const int lane = tid & 63, wid = tid >> 6;      // 8 waves: 2 (M) x 4 (N)
  const int wr = wid >> 2, wc = wid & 3;
  const int g = lane >> 4, l15 = lane & 15;
  // bijective XCD swizzle (all grids are multiples of 8)
  const int nwg = gridDim.x, bid = blockIdx.x;
  const int swz = (bid & 7) * (nwg >> 3) + (bid >> 3);
  const int m0 = (swz / nbn) * 256, n0 = (swz % nbn) * 256;
  const u16* gA = A + (size_t)m0 * K;
  const u16* gW = W + (size_t)n0 * K;
  const int nt = K >> 6;   // NOTE: assumed even (K = 1024 or 4096 here)

  f32x4 acc[8][4];
  #pragma unroll
  for (int i = 0; i < 8; ++i)
    #pragma unroll
    for (int j = 0; j < 4; ++j) acc[i][j] = (f32x4){0.f, 0.f, 0.f, 0.f};

  // stage one 128-row half-tile (16KB): 2 x global_load_lds(16B) per thread.
  // LDS dest linear; global source chunk-XOR'd (both-sides swizzle rule).
  auto stageA = [&](int b, int kt, int h){
    char* dst = lds + b * 65536 + h * 16384 + wid * 1024;
    const u16* src = gA + (size_t)(h * 128) * K + (kt << 6);
    #pragma unroll
    for (int i = 0; i < 2; ++i){
      int li = i * 512 + tid;
      int r  = li >> 3;
      int ch = (li & 7) ^ (r & 7);
      __builtin_amdgcn_global_load_lds(
        (const __attribute__((address_space(1))) u32*)(src + (size_t)r * K + ch * 8),
        (__attribute__((address_space(3))) u32*)(dst + i * 8192), 16, 0, 0);
    }
  };
  auto stageB = [&](int b, int kt, int h){
    char* dst = lds + b * 65536 + 32768 + h * 16384 + wid * 1024;
    const u16* src = gW + (size_t)(h * 128) * K + (kt << 6);
    #pragma unroll
    for (int i = 0; i < 2; ++i){
      int li = i * 512 + tid;
      int r  = li >> 3;
      int ch = (li & 7) ^ (r & 7);
      __builtin_amdgcn_global_load_lds(
        (const __attribute__((address_space(1))) u32*)(src + (size_t)r * K + ch * 8),
        (__attribute__((address_space(3))) u32*)(dst + i * 8192), 16, 0, 0);
    }
  };
  // fragment reads (swizzled)
  auto rdA = [&](bf16x8 (&d)[2][2], const char* Abase, int q){
    #pragma unroll
    for (int i = 0; i < 2; ++i)
      #pragma unroll
      for (int s = 0; s < 2; ++s){
        int row = wr * 128 + (2 * q + i) * 16 + l15;
        d[i][s] = *(const bf16x8*)(Abase + row * 128 + (((4 * s + g) ^ (row & 7)) << 4));
      }
  };
  auto rdB = [&](bf16x8 (&d)[4][2], const char* Bbase){
    #pragma unroll
    for (int nf = 0; nf < 4; ++nf)
      #pragma unroll
      for (int s = 0; s < 2; ++s){
        int row = wc * 64 + nf * 16 + l15;
        d[nf][s] = *(const bf16x8*)(Bbase + row * 128 + (((4 * s + g) ^ (row & 7)) << 4));
      }
  };

  bf16x8 bfr[2][4][2];   // [tile parity][nf][s]
  bf16x8 aQ[2][2][2];    // [quad parity][i][s]

  // ---- prologue: tile0 staged + landed; tile1 A in flight; tile0 q0 frags read ----
  stageA(0, 0, 0); stageA(0, 0, 1); stageB(0, 0, 0); stageB(0, 0, 1);
  if (nt > 1){
    stageA(1, 1, 0); stageA(1, 1, 1);
    asm volatile("s_waitcnt vmcnt(4)" ::: "memory");
  } else {
    asm volatile("s_waitcnt vmcnt(0)" ::: "memory");
  }
  __builtin_amdgcn_s_barrier();
  rdB(bfr[0], lds + 32768);
  rdA(aQ[0], lds, 0);

  for (int t0 = 0; t0 < nt; t0 += 2){
    #pragma unroll
    for (int u = 0; u < 2; ++u){
      const int t = t0 + u;
      const char* Ab  = lds + u * 65536;
      const char* Bb1 = lds + (u ^ 1) * 65536 + 32768;
      const char* Ab1 = lds + (u ^ 1) * 65536;
      // P1: quad0; read q1 frags; stage B(t+1) h0
      if (t + 1 < nt) stageB(u ^ 1, t + 1, 0);
      rdA(aQ[1], Ab, 1);
      quadf<0>(acc, aQ[0], bfr[u]);
      // P2: quad1; read q2 frags; stage B(t+1) h1
      if (t + 1 < nt) stageB(u ^ 1, t + 1, 1);
      rdA(aQ[0], Ab, 2);
      quadf<1>(acc, aQ[1], bfr[u]);
      // P3: quad2; read q3 frags; then free A-region of buf u
      rdA(aQ[1], Ab, 3);
      quadf<2>(acc, aQ[0], bfr[u]);
      asm volatile("s_waitcnt lgkmcnt(0)" ::: "memory");
      __builtin_amdgcn_s_barrier();
      // P4: stage A(t+2) into freed region; counted vmcnt; read next tile's B + q0; quad3
      if (t + 2 < nt){
        stageA(u, t + 2, 0); stageA(u, t + 2, 1);
        asm volatile("s_waitcnt vmcnt(4)" ::: "memory");  // A(t+1)+B(t+1) landed; A(t+2) in flight
      } else if (t + 1 < nt){
        asm volatile("s_waitcnt vmcnt(0)" ::: "memory");
      }
      if (t + 1 < nt){
        __builtin_amdgcn_s_barrier();
        rdB(bfr[u ^ 1], Bb1);      // overlap these reads with quad3's MFMAs
        rdA(aQ[0], Ab1, 0);
      }
      quadf<3>(acc, aQ[1], bfr[u]);
    }
  }

  // epilogue: D frag col = lane&15, row = 4*(lane>>4) + r
  #pragma unroll
  for (int mf = 0; mf < 8; ++mf){
    #pragma unroll
    for (int nf = 0; nf < 4; ++nf){
      int row = m0 + wr * 128 + mf * 16 + 4 * g;
      int col = n0 + wc * 64 + nf * 16 + l15;
      float bcol = bias[col];
      #pragma unroll
      for (int r = 0; r < 4; ++r){
        float v = acc[mf][nf][r] + bcol;
        size_t idx = (size_t)(row + r) * N + col;
        if constexpr (EPI == 0){
          ((u16*)outp)[idx] = f2bf(v);
        } else if constexpr (EPI == 1){
          ((float*)outp)[idx] = res[idx] + v;
        } else if constexpr (EPI == 2){
          ((u16*)outp)[idx] = f2bf(gelu_f(v));
        } else {
          float* o = (float*)outp; o[idx] = o[idx] + v;
        }
      }
    }
  }
}

extern "C" void kernel_launch(void* const* d_in, const int* in_sizes, int n_in,
                              void* d_out, int out_size, void* d_ws, size_t ws_size,
                              hipStream_t stream){
  (void)in_sizes; (void)n_in; (void)out_size; (void)ws_size;
  const float* x    = (const float*)d_in[0];
  const float* ln1w = (const float*)d_in[1];
  const float* ln1b = (const float*)d_in[2];
  const float* qw   = (const float*)d_in[3];
  const float* qb   = (const float*)d_in[4];
  const float* kw   = (const float*)d_in[5];
  const float* kb   = (const float*)d_in[6];
  const float* vw   = (const float*)d_in[7];
  const float* vb   = (const float*)d_in[8];
  const float* ow   = (const float*)d_in[9];
  const float* ob   = (const float*)d_in[10];
  const float* ln2w = (const float*)d_in[11];
  const float* ln2b = (const float*)d_in[12];
  const float* fcw  = (const float*)d_in[13];
  const float* fcb  = (const float*)d_in[14];
  const float* pw   = (const float*)d_in[15];
  const float* pb   = (const float*)d_in[16];

  char* ws = (char*)d_ws;
  u16*   WQKV = (u16*)(ws + 0);              // [3072][1024] bf16 (q_w|k_w|v_w)
  u16*   WO   = (u16*)(ws + 6291456);        // [1024][1024]
  u16*   WFC  = (u16*)(ws + 8388608);        // [4096][1024]
  u16*   WPR  = (u16*)(ws + 16777216);       // [1024][4096]
  float* BQ   = (float*)(ws + 25165824);     // [3072]
  u16*   XN   = (u16*)(ws + 25178112);       // [16384][1024] bf16 (xn, reused for xn2)
  u16*   QKV  = (u16*)(ws + 58732544);       // [16384][3072] bf16
  u16*   ATT  = (u16*)(ws + 159395840);      // [16384][1024] bf16
  u16*   H    = QKV;                          // [16384][4096] bf16, reuses QKV+ATT region
  float* OUT  = (float*)d_out;               // x1 intermediate, then final output

  // weight casts (fp32 -> bf16)
  k_cast<<<512, 256, 0, stream>>>(qw, WQKV,           262144);
  k_cast<<<512, 256, 0, stream>>>(kw, WQKV + 1048576, 262144);
  k_cast<<<512, 256, 0, stream>>>(vw, WQKV + 2097152, 262144);
  k_cast<<<512, 256, 0, stream>>>(ow, WO,             262144);
  k_cast<<<1024, 256, 0, stream>>>(fcw, WFC,          1048576);
  k_cast<<<1024, 256, 0, stream>>>(pw,  WPR,          1048576);
  k_cat3<<<12, 256, 0, stream>>>(qb, kb, vb, BQ);

  // ln1 -> fused QKV gemm -> per-token attention -> O gemm (+x residual) -> OUT (x1)
  k_ln<<<16384, 256, 0, stream>>>(x, ln1w, ln1b, XN);
  k_gemm<0><<<64 * 12, 512, 0, stream>>>(XN, WQKV, BQ, nullptr, QKV, 3072, 1024, 12);
  k_attn<<<4096, 256, 0, stream>>>(QKV, ATT);
  k_gemm<1><<<64 * 4, 512, 0, stream>>>(ATT, WO, ob, x, OUT, 1024, 1024, 4);

  // ln2 -> FC gemm (+gelu) -> PROJ gemm (+x1 residual, in place on OUT)
  k_ln<<<16384, 256, 0, stream>>>(OUT, ln2w, ln2b, XN);
  k_gemm<2><<<64 * 16, 512, 0, stream>>>(XN, WFC, fcb, nullptr, H, 4096, 1024, 16);
  k_gemm<3><<<64 * 4, 512, 0, stream>>>(H, WPR, pb, nullptr, OUT, 1024, 4096, 4);
}

// Round 4
// 580.623 us; speedup vs baseline: 1.4686x; 1.4686x over previous
//
#include <hip/hip_runtime.h>
#include <math.h>

typedef unsigned short u16;
typedef unsigned int   u32;
typedef __attribute__((ext_vector_type(8))) short bf16x8;          // 8 bf16 = 4 VGPR (MFMA A/B frag)
typedef __attribute__((ext_vector_type(4))) float f32x4;           // MFMA C/D frag
typedef __attribute__((ext_vector_type(4))) unsigned short u16x4;

__device__ __forceinline__ float bf2f(u16 v){ return __uint_as_float(((u32)v) << 16); }
__device__ __forceinline__ u16 f2bf(float f){
  u32 u = __float_as_uint(f);
  return (u16)((u + 0x7fffu + ((u >> 16) & 1u)) >> 16);  // RNE
}
__device__ __forceinline__ float elu1(float x){ return x > 0.f ? x + 1.f : __expf(x); }
__device__ __forceinline__ float gelu_f(float v){
  float u = 0.7978845608f * (v + 0.044715f * v * v * v);
  float e = __expf(-2.f * fabsf(u));
  float th = copysignf((1.f - e) / (1.f + e), u);
  return 0.5f * v * (1.f + th);
}

// ---------------- cast f32 -> bf16, vectorized x4 ----------------
__global__ __launch_bounds__(256) void k_cast(const float* __restrict__ src, u16* __restrict__ dst, int n4){
  int i = blockIdx.x * 256 + threadIdx.x;
  int stride = gridDim.x * 256;
  for (; i < n4; i += stride){
    float4 v = ((const float4*)src)[i];
    u16x4 o; o.x = f2bf(v.x); o.y = f2bf(v.y); o.z = f2bf(v.z); o.w = f2bf(v.w);
    ((u16x4*)dst)[i] = o;
  }
}

// concat q_b,k_b,v_b -> one 3072-float bias
__global__ void k_cat3(const float* __restrict__ a, const float* __restrict__ b,
                       const float* __restrict__ c, float* __restrict__ dst){
  int i = blockIdx.x * 256 + threadIdx.x;
  dst[i] = i < 1024 ? a[i] : (i < 2048 ? b[i - 1024] : c[i - 2048]);
}

// ---------------- LayerNorm over C=1024: f32 in -> bf16 out ----------------
__global__ __launch_bounds__(256) void k_ln(const float* __restrict__ x, const float* __restrict__ w,
                                            const float* __restrict__ b, u16* __restrict__ out){
  const int t = threadIdx.x;
  const size_t m = blockIdx.x;
  float4 v = ((const float4*)(x + m * 1024))[t];
  float s  = v.x + v.y + v.z + v.w;
  float s2 = v.x*v.x + v.y*v.y + v.z*v.z + v.w*v.w;
  #pragma unroll
  for (int o = 32; o > 0; o >>= 1){ s += __shfl_down(s, o, 64); s2 += __shfl_down(s2, o, 64); }
  __shared__ float red[8];
  if ((t & 63) == 0){ red[t >> 6] = s; red[4 + (t >> 6)] = s2; }
  __syncthreads();
  s  = red[0] + red[1] + red[2] + red[3];
  s2 = red[4] + red[5] + red[6] + red[7];
  float mu  = s * (1.f / 1024.f);
  float inv = rsqrtf(s2 * (1.f / 1024.f) - mu * mu + 1e-5f);
  float4 wv = ((const float4*)w)[t];
  float4 bv = ((const float4*)b)[t];
  u16x4 o;
  o.x = f2bf((v.x - mu) * inv * wv.x + bv.x);
  o.y = f2bf((v.y - mu) * inv * wv.y + bv.y);
  o.z = f2bf((v.z - mu) * inv * wv.z + bv.z);
  o.w = f2bf((v.w - mu) * inv * wv.w + bv.w);
  ((u16x4*)(out + m * 1024))[t] = o;
}

// ---------------- per-token linear attention ----------------
__global__ __launch_bounds__(256) void k_attn(const u16* __restrict__ qkv, u16* __restrict__ out){
  __shared__ float qe[4][16][68];
  __shared__ float ke[4][16][68];
  __shared__ float sm[4][16][20];
  const int w = threadIdx.x >> 6, lane = threadIdx.x & 63;
  const size_t m = (size_t)blockIdx.x * 4 + w;
  const u16* base = qkv + m * 3072;
  #pragma unroll
  for (int i = 0; i < 8; ++i){
    int idx = i * 64 + lane;
    int h = idx >> 5, c2 = (idx & 31) * 2;
    u32 qv = ((const u32*)base)[idx];
    u32 kv = ((const u32*)base)[512 + idx];
    float2 qf, kf;
    qf.x = elu1(bf2f((u16)(qv & 0xffffu))); qf.y = elu1(bf2f((u16)(qv >> 16)));
    kf.x = elu1(bf2f((u16)(kv & 0xffffu))); kf.y = elu1(bf2f((u16)(kv >> 16)));
    *(float2*)&qe[w][h][c2] = qf;
    *(float2*)&ke[w][h][c2] = kf;
  }
  float vr[16];
  #pragma unroll
  for (int h = 0; h < 16; ++h) vr[h] = bf2f(base[2048 + h * 64 + lane]);
  __syncthreads();
  const int sh = lane >> 2, jb = lane & 3;
  float sacc[4] = {0.f, 0.f, 0.f, 0.f};
  #pragma unroll
  for (int d4 = 0; d4 < 16; ++d4){
    float4 q4 = *(const float4*)&qe[w][sh][d4 * 4];
    #pragma unroll
    for (int j = 0; j < 4; ++j){
      float4 k4 = *(const float4*)&ke[w][4 * jb + j][d4 * 4];
      sacc[j] += q4.x*k4.x + q4.y*k4.y + q4.z*k4.z + q4.w*k4.w;
    }
  }
  #pragma unroll
  for (int j = 0; j < 4; ++j) sm[w][sh][4 * jb + j] = sacc[j];
  float part = sacc[0] + sacc[1] + sacc[2] + sacc[3];
  part += __shfl_xor(part, 1, 64);
  part += __shfl_xor(part, 2, 64);
  if (jb == 0) sm[w][sh][16] = part;
  __syncthreads();
  float acc[16];
  #pragma unroll
  for (int h = 0; h < 16; ++h) acc[h] = 0.f;
  #pragma unroll
  for (int h = 0; h < 16; ++h){
    #pragma unroll
    for (int j4 = 0; j4 < 4; ++j4){
      float4 s4 = *(const float4*)&sm[w][h][j4 * 4];
      acc[h] += s4.x*vr[4*j4] + s4.y*vr[4*j4+1] + s4.z*vr[4*j4+2] + s4.w*vr[4*j4+3];
    }
  }
  u16* ob = out + m * 1024;
  #pragma unroll
  for (int h = 0; h < 16; ++h)
    ob[h * 64 + lane] = f2bf(acc[h] / sm[w][h][16]);
}

// ---------------- 256x256-tile 8-wave bf16 GEMM — m201 8-phase template ----------------
// Per K-tile: 4 phases, one C-quadrant (16 MFMA over BK=64) each.
// Phase = {ds_reads; stage; barrier; lgkmcnt(0); setprio MFMA setprio; barrier}; vmcnt(4) once/tile.
// C = A(M,K) * W(N,K)^T + bias.  EPI 0: bf16 out  1: f32 = res + v  2: bf16 = gelu(v)  3: f32 += v
template<int QM, int QN>
__device__ __forceinline__ void quad16(f32x4 (&acc)[8][4], const bf16x8 (&a)[4][2], const bf16x8 (&b)[2][2]){
  __builtin_amdgcn_s_setprio(1);
  #pragma unroll
  for (int s = 0; s < 2; ++s)
    #pragma unroll
    for (int i = 0; i < 4; ++i)
      #pragma unroll
      for (int j = 0; j < 2; ++j)
        acc[QM*4+i][QN*2+j] = __builtin_amdgcn_mfma_f32_16x16x32_bf16(a[i][s], b[j][s], acc[QM*4+i][QN*2+j], 0, 0, 0);
  __builtin_amdgcn_s_setprio(0);
}

template<int EPI>
__global__ __launch_bounds__(512, 2) void k_gemm(const u16* __restrict__ A, const u16* __restrict__ W,
                                                 const float* __restrict__ bias, const float* __restrict__ res,
                                                 void* __restrict__ outp, int N, int K, int nbn){
  __shared__ alignas(16) char lds[131072];   // buf b: A @ b*65536 (32K), B @ b*65536+32768 (32K)
  const int tid  = threadIdx.x;
  const int lane = tid & 63, wid = tid >> 6;      // 8 waves: 2 (M) x 4 (N)
  const int wr = wid >> 2, wc = wid & 3;
  const int g = lane >> 4, l15 = lane & 15;
  // bijective XCD swizzle (all grids are multiples of 8)
  const int nwg = gridDim.x, bid = blockIdx.x;
  const int swz = (bid & 7) * (nwg >> 3) + (bid >> 3);
  const int m0 = (swz / nbn) * 256, n0 = (swz % nbn) * 256;
  const u16* gA = A + (size_t)m0 * K;
  const u16* gW = W + (size_t)n0 * K;
  const int nt = K >> 6;

  f32x4 acc[8][4];
  #pragma unroll
  for (int i = 0; i < 8; ++i)
    #pragma unroll
    for (int j = 0; j < 4; ++j) acc[i][j] = (f32x4){0.f, 0.f, 0.f, 0.f};

  // stage one 128-row half-tile (16KB): 2 x global_load_lds(16B) per thread.
  // LDS dest linear; global source chunk-XOR'd (both-sides swizzle rule).
  auto stageA = [&](int b, int kt, int h){
    char* dst = lds + b * 65536 + h * 16384 + wid * 1024;
    const u16* src = gA + (size_t)(h * 128) * K + (kt << 6);
    #pragma unroll
    for (int i = 0; i < 2; ++i){
      int li = i * 512 + tid;
      int r  = li >> 3;
      int ch = (li & 7) ^ (r & 7);
      __builtin_amdgcn_global_load_lds(
        (const __attribute__((address_space(1))) u32*)(src + (size_t)r * K + ch * 8),
        (__attribute__((address_space(3))) u32*)(dst + i * 8192), 16, 0, 0);
    }
  };
  auto stageB = [&](int b, int kt, int h){
    char* dst = lds + b * 65536 + 32768 + h * 16384 + wid * 1024;
    const u16* src = gW + (size_t)(h * 128) * K + (kt << 6);
    #pragma unroll
    for (int i = 0; i < 2; ++i){
      int li = i * 512 + tid;
      int r  = li >> 3;
      int ch = (li & 7) ^ (r & 7);
      __builtin_amdgcn_global_load_lds(
        (const __attribute__((address_space(1))) u32*)(src + (size_t)r * K + ch * 8),
        (__attribute__((address_space(3))) u32*)(dst + i * 8192), 16, 0, 0);
    }
  };
  // fragment reads (swizzled): A quadrant-half (4 frag-rows x 2 k-slices)
  auto rdA4 = [&](bf16x8 (&d)[4][2], const char* Abase, int qm){
    #pragma unroll
    for (int i = 0; i < 4; ++i)
      #pragma unroll
      for (int s = 0; s < 2; ++s){
        int row = wr * 128 + (qm * 4 + i) * 16 + l15;
        d[i][s] = *(const bf16x8*)(Abase + row * 128 + (((4 * s + g) ^ (row & 7)) << 4));
      }
  };
  // B quadrant (2 frag-cols x 2 k-slices)
  auto rdB2 = [&](bf16x8 (&d)[2][2], const char* Bbase, int qn){
    #pragma unroll
    for (int j = 0; j < 2; ++j)
      #pragma unroll
      for (int s = 0; s < 2; ++s){
        int row = wc * 64 + (qn * 2 + j) * 16 + l15;
        d[j][s] = *(const bf16x8*)(Bbase + row * 128 + (((4 * s + g) ^ (row & 7)) << 4));
      }
  };

  bf16x8 aA[4][2];        // current A quadrant-half (qm0 in P1-P2, qm1 in P3-P4)
  bf16x8 bB[2][2][2];     // [qn][j][s] — both qn groups live all 4 phases

  // ---- prologue: tile0 staged + landed; tile1 A in flight ----
  stageA(0, 0, 0); stageA(0, 0, 1); stageB(0, 0, 0); stageB(0, 0, 1);
  if (nt > 1){
    stageA(1, 1, 0); stageA(1, 1, 1);
    asm volatile("s_waitcnt vmcnt(4)" ::: "memory");   // tile0's 8 loads landed; tile1 A (4) in flight
  } else {
    asm volatile("s_waitcnt vmcnt(0)" ::: "memory");
  }
  __builtin_amdgcn_s_barrier();

  for (int t = 0; t < nt; ++t){
    const int c = t & 1;
    const char* Ab = lds + c * 65536;
    const char* Bb = Ab + 32768;

    // ---- P1: read B qn0 (4) + A qm0 (8); stage B(t+1)h0; quad (0,0) ----
    rdB2(bB[0], Bb, 0);
    rdA4(aA, Ab, 0);
    if (t + 1 < nt) stageB(c ^ 1, t + 1, 0);
    __builtin_amdgcn_s_barrier();
    asm volatile("s_waitcnt lgkmcnt(0)" ::: "memory");
    quad16<0, 0>(acc, aA, bB[0]);
    __builtin_amdgcn_s_barrier();

    // ---- P2: read B qn1 (4); stage B(t+1)h1; quad (0,1) ----
    rdB2(bB[1], Bb, 1);
    if (t + 1 < nt) stageB(c ^ 1, t + 1, 1);
    __builtin_amdgcn_s_barrier();
    asm volatile("s_waitcnt lgkmcnt(0)" ::: "memory");
    quad16<0, 1>(acc, aA, bB[1]);
    __builtin_amdgcn_s_barrier();

    // ---- P3: read A qm1 (8); quad (1,0) ----
    rdA4(aA, Ab, 1);
    __builtin_amdgcn_s_barrier();
    asm volatile("s_waitcnt lgkmcnt(0)" ::: "memory");
    quad16<1, 0>(acc, aA, bB[0]);
    __builtin_amdgcn_s_barrier();

    // ---- P4: stage A(t+2) into freed A-region (all waves' A-reads done after P3); quad (1,1); vmcnt ----
    if (t + 2 < nt){ stageA(c, t + 2, 0); stageA(c, t + 2, 1); }
    __builtin_amdgcn_s_barrier();
    quad16<1, 1>(acc, aA, bB[1]);
    if (t + 2 < nt){
      asm volatile("s_waitcnt vmcnt(4)" ::: "memory");  // A(t+1)+B(t+1) landed; A(t+2) still in flight
    } else {
      asm volatile("s_waitcnt vmcnt(0)" ::: "memory");  // tail: drain
    }
    __builtin_amdgcn_s_barrier();
  }

  // epilogue: D frag col = lane&15, row = 4*(lane>>4) + r
  #pragma unroll
  for (int mf = 0; mf < 8; ++mf){
    #pragma unroll
    for (int nf = 0; nf < 4; ++nf){
      int row = m0 + wr * 128 + mf * 16 + 4 * g;
      int col = n0 + wc * 64 + nf * 16 + l15;
      float bcol = bias[col];
      #pragma unroll
      for (int r = 0; r < 4; ++r){
        float v = acc[mf][nf][r] + bcol;
        size_t idx = (size_t)(row + r) * N + col;
        if constexpr (EPI == 0){
          ((u16*)outp)[idx] = f2bf(v);
        } else if constexpr (EPI == 1){
          ((float*)outp)[idx] = res[idx] + v;
        } else if constexpr (EPI == 2){
          ((u16*)outp)[idx] = f2bf(gelu_f(v));
        } else {
          float* o = (float*)outp; o[idx] = o[idx] + v;
        }
      }
    }
  }
}

extern "C" void kernel_launch(void* const* d_in, const int* in_sizes, int n_in,
                              void* d_out, int out_size, void* d_ws, size_t ws_size,
                              hipStream_t stream){
  (void)in_sizes; (void)n_in; (void)out_size; (void)ws_size;
  const float* x    = (const float*)d_in[0];
  const float* ln1w = (const float*)d_in[1];
  const float* ln1b = (const float*)d_in[2];
  const float* qw   = (const float*)d_in[3];
  const float* qb   = (const float*)d_in[4];
  const float* kw   = (const float*)d_in[5];
  const float* kb   = (const float*)d_in[6];
  const float* vw   = (const float*)d_in[7];
  const float* vb   = (const float*)d_in[8];
  const float* ow   = (const float*)d_in[9];
  const float* ob   = (const float*)d_in[10];
  const float* ln2w = (const float*)d_in[11];
  const float* ln2b = (const float*)d_in[12];
  const float* fcw  = (const float*)d_in[13];
  const float* fcb  = (const float*)d_in[14];
  const float* pw   = (const float*)d_in[15];
  const float* pb   = (const float*)d_in[16];

  char* ws = (char*)d_ws;
  u16*   WQKV = (u16*)(ws + 0);              // [3072][1024] bf16 (q_w|k_w|v_w)
  u16*   WO   = (u16*)(ws + 6291456);        // [1024][1024]
  u16*   WFC  = (u16*)(ws + 8388608);        // [4096][1024]
  u16*   WPR  = (u16*)(ws + 16777216);       // [1024][4096]
  float* BQ   = (float*)(ws + 25165824);     // [3072]
  u16*   XN   = (u16*)(ws + 25178112);       // [16384][1024] bf16 (xn, reused for xn2)
  u16*   QKV  = (u16*)(ws + 58732544);       // [16384][3072] bf16
  u16*   ATT  = (u16*)(ws + 159395840);      // [16384][1024] bf16
  u16*   H    = QKV;                          // [16384][4096] bf16, reuses QKV+ATT region
  float* OUT  = (float*)d_out;               // x1 intermediate, then final output

  // weight casts (fp32 -> bf16)
  k_cast<<<512, 256, 0, stream>>>(qw, WQKV,           262144);
  k_cast<<<512, 256, 0, stream>>>(kw, WQKV + 1048576, 262144);
  k_cast<<<512, 256, 0, stream>>>(vw, WQKV + 2097152, 262144);
  k_cast<<<512, 256, 0, stream>>>(ow, WO,             262144);
  k_cast<<<1024, 256, 0, stream>>>(fcw, WFC,          1048576);
  k_cast<<<1024, 256, 0, stream>>>(pw,  WPR,          1048576);
  k_cat3<<<12, 256, 0, stream>>>(qb, kb, vb, BQ);

  // ln1 -> fused QKV gemm -> per-token attention -> O gemm (+x residual) -> OUT (x1)
  k_ln<<<16384, 256, 0, stream>>>(x, ln1w, ln1b, XN);
  k_gemm<0><<<64 * 12, 512, 0, stream>>>(XN, WQKV, BQ, nullptr, QKV, 3072, 1024, 12);
  k_attn<<<4096, 256, 0, stream>>>(QKV, ATT);
  k_gemm<1><<<64 * 4, 512, 0, stream>>>(ATT, WO, ob, x, OUT, 1024, 1024, 4);

  // ln2 -> FC gemm (+gelu) -> PROJ gemm (+x1 residual, in place on OUT)
  k_ln<<<16384, 256, 0, stream>>>(OUT, ln2w, ln2b, XN);
  k_gemm<2><<<64 * 16, 512, 0, stream>>>(XN, WFC, fcb, nullptr, H, 4096, 1024, 16);
  k_gemm<3><<<64 * 4, 512, 0, stream>>>(H, WPR, pb, nullptr, OUT, 1024, 4096, 4);
}

// Round 5
// 571.436 us; speedup vs baseline: 1.4922x; 1.0161x over previous
//
#include <hip/hip_runtime.h>
#include <math.h>

typedef unsigned short u16;
typedef unsigned int   u32;
typedef __attribute__((ext_vector_type(8))) short bf16x8;          // 8 bf16 = 4 VGPR (MFMA A/B frag)
typedef __attribute__((ext_vector_type(4))) float f32x4;           // MFMA C/D frag
typedef __attribute__((ext_vector_type(4))) unsigned short u16x4;

__device__ __forceinline__ float bf2f(u16 v){ return __uint_as_float(((u32)v) << 16); }
__device__ __forceinline__ u16 f2bf(float f){
  u32 u = __float_as_uint(f);
  return (u16)((u + 0x7fffu + ((u >> 16) & 1u)) >> 16);  // RNE
}
__device__ __forceinline__ float elu1(float x){ return x > 0.f ? x + 1.f : __expf(x); }
__device__ __forceinline__ float gelu_f(float v){
  float u = 0.7978845608f * (v + 0.044715f * v * v * v);
  float e = __expf(-2.f * fabsf(u));
  float th = copysignf((1.f - e) / (1.f + e), u);
  return 0.5f * v * (1.f + th);
}

// ---------------- cast f32 -> bf16, vectorized x4 ----------------
__global__ __launch_bounds__(256) void k_cast(const float* __restrict__ src, u16* __restrict__ dst, int n4){
  int i = blockIdx.x * 256 + threadIdx.x;
  int stride = gridDim.x * 256;
  for (; i < n4; i += stride){
    float4 v = ((const float4*)src)[i];
    u16x4 o; o.x = f2bf(v.x); o.y = f2bf(v.y); o.z = f2bf(v.z); o.w = f2bf(v.w);
    ((u16x4*)dst)[i] = o;
  }
}

// concat q_b,k_b,v_b -> one 3072-float bias
__global__ void k_cat3(const float* __restrict__ a, const float* __restrict__ b,
                       const float* __restrict__ c, float* __restrict__ dst){
  int i = blockIdx.x * 256 + threadIdx.x;
  dst[i] = i < 1024 ? a[i] : (i < 2048 ? b[i - 1024] : c[i - 2048]);
}

// ---------------- LayerNorm over C=1024: f32 in -> bf16 out ----------------
__global__ __launch_bounds__(256) void k_ln(const float* __restrict__ x, const float* __restrict__ w,
                                            const float* __restrict__ b, u16* __restrict__ out){
  const int t = threadIdx.x;
  const size_t m = blockIdx.x;
  float4 v = ((const float4*)(x + m * 1024))[t];
  float s  = v.x + v.y + v.z + v.w;
  float s2 = v.x*v.x + v.y*v.y + v.z*v.z + v.w*v.w;
  #pragma unroll
  for (int o = 32; o > 0; o >>= 1){ s += __shfl_down(s, o, 64); s2 += __shfl_down(s2, o, 64); }
  __shared__ float red[8];
  if ((t & 63) == 0){ red[t >> 6] = s; red[4 + (t >> 6)] = s2; }
  __syncthreads();
  s  = red[0] + red[1] + red[2] + red[3];
  s2 = red[4] + red[5] + red[6] + red[7];
  float mu  = s * (1.f / 1024.f);
  float inv = rsqrtf(s2 * (1.f / 1024.f) - mu * mu + 1e-5f);
  float4 wv = ((const float4*)w)[t];
  float4 bv = ((const float4*)b)[t];
  u16x4 o;
  o.x = f2bf((v.x - mu) * inv * wv.x + bv.x);
  o.y = f2bf((v.y - mu) * inv * wv.y + bv.y);
  o.z = f2bf((v.z - mu) * inv * wv.z + bv.z);
  o.w = f2bf((v.w - mu) * inv * wv.w + bv.w);
  ((u16x4*)(out + m * 1024))[t] = o;
}

// ---------------- per-token linear attention ----------------
__global__ __launch_bounds__(256) void k_attn(const u16* __restrict__ qkv, u16* __restrict__ out){
  __shared__ float qe[4][16][68];
  __shared__ float ke[4][16][68];
  __shared__ float sm[4][16][20];
  const int w = threadIdx.x >> 6, lane = threadIdx.x & 63;
  const size_t m = (size_t)blockIdx.x * 4 + w;
  const u16* base = qkv + m * 3072;
  #pragma unroll
  for (int i = 0; i < 8; ++i){
    int idx = i * 64 + lane;
    int h = idx >> 5, c2 = (idx & 31) * 2;
    u32 qv = ((const u32*)base)[idx];
    u32 kv = ((const u32*)base)[512 + idx];
    float2 qf, kf;
    qf.x = elu1(bf2f((u16)(qv & 0xffffu))); qf.y = elu1(bf2f((u16)(qv >> 16)));
    kf.x = elu1(bf2f((u16)(kv & 0xffffu))); kf.y = elu1(bf2f((u16)(kv >> 16)));
    *(float2*)&qe[w][h][c2] = qf;
    *(float2*)&ke[w][h][c2] = kf;
  }
  float vr[16];
  #pragma unroll
  for (int h = 0; h < 16; ++h) vr[h] = bf2f(base[2048 + h * 64 + lane]);
  __syncthreads();
  const int sh = lane >> 2, jb = lane & 3;
  float sacc[4] = {0.f, 0.f, 0.f, 0.f};
  #pragma unroll
  for (int d4 = 0; d4 < 16; ++d4){
    float4 q4 = *(const float4*)&qe[w][sh][d4 * 4];
    #pragma unroll
    for (int j = 0; j < 4; ++j){
      float4 k4 = *(const float4*)&ke[w][4 * jb + j][d4 * 4];
      sacc[j] += q4.x*k4.x + q4.y*k4.y + q4.z*k4.z + q4.w*k4.w;
    }
  }
  #pragma unroll
  for (int j = 0; j < 4; ++j) sm[w][sh][4 * jb + j] = sacc[j];
  float part = sacc[0] + sacc[1] + sacc[2] + sacc[3];
  part += __shfl_xor(part, 1, 64);
  part += __shfl_xor(part, 2, 64);
  if (jb == 0) sm[w][sh][16] = part;
  __syncthreads();
  float acc[16];
  #pragma unroll
  for (int h = 0; h < 16; ++h) acc[h] = 0.f;
  #pragma unroll
  for (int h = 0; h < 16; ++h){
    #pragma unroll
    for (int j4 = 0; j4 < 4; ++j4){
      float4 s4 = *(const float4*)&sm[w][h][j4 * 4];
      acc[h] += s4.x*vr[4*j4] + s4.y*vr[4*j4+1] + s4.z*vr[4*j4+2] + s4.w*vr[4*j4+3];
    }
  }
  u16* ob = out + m * 1024;
  #pragma unroll
  for (int h = 0; h < 16; ++h)
    ob[h * 64 + lane] = f2bf(acc[h] / sm[w][h][16]);
}

// ---------------- 256x256-tile 8-wave bf16 GEMM — read-ahead counted-lgkm schedule ----------------
// Per K-tile (buf c, BK=64 = 2 k-slices): 4 phases consume (qm,s) = (0,0),(0,1),(1,0),(1,1).
// Read group G_{p+1} is issued BEFORE phase p's MFMA (pinned by the phase barrier), so its LDS
// service overlaps the matrix pipe; each MFMA waits on a counted lgkmcnt (8/4/4), never 0 mid-tile.
// Hazards: stageA(c,t+2) only after all-waves lgkm(0)-on-G4 + barrier; G1(t+1) only after
// vmcnt(4)+barrier (12 outstanding -> leaves exactly A(t+2)).
// C = A(M,K) * W(N,K)^T + bias.  EPI 0: bf16 out  1: f32 = res + v  2: bf16 = gelu(v)  3: f32 += v
template<int QM>
__device__ __forceinline__ void quad16(f32x4 (&acc)[8][4], const bf16x8 (&a)[4], const bf16x8 (&b)[4]){
  __builtin_amdgcn_s_setprio(1);
  #pragma unroll
  for (int i = 0; i < 4; ++i)
    #pragma unroll
    for (int nf = 0; nf < 4; ++nf)
      acc[QM*4+i][nf] = __builtin_amdgcn_mfma_f32_16x16x32_bf16(a[i], b[nf], acc[QM*4+i][nf], 0, 0, 0);
  __builtin_amdgcn_s_setprio(0);
}

template<int EPI>
__global__ __launch_bounds__(512, 2) void k_gemm(const u16* __restrict__ A, const u16* __restrict__ W,
                                                 const float* __restrict__ bias, const float* __restrict__ res,
                                                 void* __restrict__ outp, int N, int K, int nbn){
  __shared__ alignas(16) char lds[131072];   // buf b: A @ b*65536 (32K), B @ b*65536+32768 (32K)
  const int tid  = threadIdx.x;
  const int lane = tid & 63, wid = tid >> 6;      // 8 waves: 2 (M) x 4 (N)
  const int wr = wid >> 2, wc = wid & 3;
  const int g = lane >> 4, l15 = lane & 15;
  // bijective XCD swizzle (all grids are multiples of 8)
  const int nwg = gridDim.x, bid = blockIdx.x;
  const int swz = (bid & 7) * (nwg >> 3) + (bid >> 3);
  const int m0 = (swz / nbn) * 256, n0 = (swz % nbn) * 256;
  const u16* gA = A + (size_t)m0 * K;
  const u16* gW = W + (size_t)n0 * K;
  const int nt = K >> 6;

  f32x4 acc[8][4];
  #pragma unroll
  for (int i = 0; i < 8; ++i)
    #pragma unroll
    for (int j = 0; j < 4; ++j) acc[i][j] = (f32x4){0.f, 0.f, 0.f, 0.f};

  // stage one 128-row half-tile (16KB): 2 x global_load_lds(16B) per thread.
  // LDS dest linear; global source chunk-XOR'd (both-sides swizzle rule).
  auto stageA = [&](int b, int kt, int h){
    char* dst = lds + b * 65536 + h * 16384 + wid * 1024;
    const u16* src = gA + (size_t)(h * 128) * K + (kt << 6);
    #pragma unroll
    for (int i = 0; i < 2; ++i){
      int li = i * 512 + tid;
      int r  = li >> 3;
      int ch = (li & 7) ^ (r & 7);
      __builtin_amdgcn_global_load_lds(
        (const __attribute__((address_space(1))) u32*)(src + (size_t)r * K + ch * 8),
        (__attribute__((address_space(3))) u32*)(dst + i * 8192), 16, 0, 0);
    }
  };
  auto stageB = [&](int b, int kt, int h){
    char* dst = lds + b * 65536 + 32768 + h * 16384 + wid * 1024;
    const u16* src = gW + (size_t)(h * 128) * K + (kt << 6);
    #pragma unroll
    for (int i = 0; i < 2; ++i){
      int li = i * 512 + tid;
      int r  = li >> 3;
      int ch = (li & 7) ^ (r & 7);
      __builtin_amdgcn_global_load_lds(
        (const __attribute__((address_space(1))) u32*)(src + (size_t)r * K + ch * 8),
        (__attribute__((address_space(3))) u32*)(dst + i * 8192), 16, 0, 0);
    }
  };
  // fragment reads (swizzled), one k-slice s at a time
  auto rdA = [&](bf16x8 (&d)[4], const char* Abase, int qm, int s){
    #pragma unroll
    for (int i = 0; i < 4; ++i){
      int row = wr * 128 + (qm * 4 + i) * 16 + l15;
      d[i] = *(const bf16x8*)(Abase + row * 128 + (((4 * s + g) ^ (row & 7)) << 4));
    }
  };
  auto rdB = [&](bf16x8 (&d)[4], const char* Bbase, int s){
    #pragma unroll
    for (int nf = 0; nf < 4; ++nf){
      int row = wc * 64 + nf * 16 + l15;
      d[nf] = *(const bf16x8*)(Bbase + row * 128 + (((4 * s + g) ^ (row & 7)) << 4));
    }
  };

  bf16x8 aP0[4], aP1[4];     // A ping-pong: G1->aP0, G2->aP1, G3->aP0, G4->aP1
  bf16x8 bS0[4], bS1[4];     // B slices: s0 (G1), s1 (G2) — live whole tile

  // ---- prologue: tile0 staged + landed; tile1 A in flight; issue G1(0) ----
  stageA(0, 0, 0); stageA(0, 0, 1); stageB(0, 0, 0); stageB(0, 0, 1);
  if (nt > 1){
    stageA(1, 1, 0); stageA(1, 1, 1);
    asm volatile("s_waitcnt vmcnt(4)" ::: "memory");   // tile0's 8 loads landed; tile1 A (4) in flight
  } else {
    asm volatile("s_waitcnt vmcnt(0)" ::: "memory");
  }
  __builtin_amdgcn_s_barrier();
  rdA(aP0, lds, 0, 0);           // G1(0): A[qm0,s0] + B[s0]
  rdB(bS0, lds + 32768, 0);

  for (int t = 0; t < nt; ++t){
    const int c = t & 1;
    const char* Ab = lds + c * 65536;
    const char* Bb = Ab + 32768;
    const char* AbN = lds + (c ^ 1) * 65536;   // next tile's buffers
    const char* BbN = AbN + 32768;

    // ---- P1: issue G2 = A[qm0,s1]+B[s1]; stage B(t+1)h0; MFMA(qm0,s0) ----
    rdA(aP1, Ab, 0, 1);
    rdB(bS1, Bb, 1);
    if (t + 1 < nt) stageB(c ^ 1, t + 1, 0);
    __builtin_amdgcn_s_barrier();
    asm volatile("s_waitcnt lgkmcnt(8)" ::: "memory");   // G1 done; G2 (8) outstanding
    quad16<0>(acc, aP0, bS0);
    __builtin_amdgcn_s_barrier();

    // ---- P2: issue G3 = A[qm1,s0]; stage B(t+1)h1; MFMA(qm0,s1) ----
    rdA(aP0, Ab, 1, 0);
    if (t + 1 < nt) stageB(c ^ 1, t + 1, 1);
    __builtin_amdgcn_s_barrier();
    asm volatile("s_waitcnt lgkmcnt(4)" ::: "memory");   // G2 done; G3 (4) outstanding
    quad16<0>(acc, aP1, bS1);
    __builtin_amdgcn_s_barrier();

    // ---- P3: issue G4 = A[qm1,s1]; MFMA(qm1,s0); then drain G4 + barrier (frees A-region) ----
    rdA(aP1, Ab, 1, 1);
    __builtin_amdgcn_s_barrier();
    asm volatile("s_waitcnt lgkmcnt(4)" ::: "memory");   // G3 done; G4 (4) outstanding
    quad16<1>(acc, aP0, bS0);
    asm volatile("s_waitcnt lgkmcnt(0)" ::: "memory");   // G4 done (all waves, pre-barrier)
    __builtin_amdgcn_s_barrier();

    // ---- P4: stage A(t+2) into freed A-region; MFMA(qm1,s1); counted vmcnt; issue G1(t+1) ----
    if (t + 2 < nt){ stageA(c, t + 2, 0); stageA(c, t + 2, 1); }
    quad16<1>(acc, aP1, bS1);
    if (t + 2 < nt){
      asm volatile("s_waitcnt vmcnt(4)" ::: "memory");   // A(t+1)+B(t+1) landed; A(t+2) in flight
    } else {
      asm volatile("s_waitcnt vmcnt(0)" ::: "memory");   // tail: drain
    }
    __builtin_amdgcn_s_barrier();                        // buf c^1 globally valid
    if (t + 1 < nt){
      rdA(aP0, AbN, 0, 0);       // G1(t+1)
      rdB(bS0, BbN, 0);
    }
  }

  // epilogue: D frag col = lane&15, row = 4*(lane>>4) + r
  #pragma unroll
  for (int mf = 0; mf < 8; ++mf){
    #pragma unroll
    for (int nf = 0; nf < 4; ++nf){
      int row = m0 + wr * 128 + mf * 16 + 4 * g;
      int col = n0 + wc * 64 + nf * 16 + l15;
      float bcol = bias[col];
      #pragma unroll
      for (int r = 0; r < 4; ++r){
        float v = acc[mf][nf][r] + bcol;
        size_t idx = (size_t)(row + r) * N + col;
        if constexpr (EPI == 0){
          ((u16*)outp)[idx] = f2bf(v);
        } else if constexpr (EPI == 1){
          ((float*)outp)[idx] = res[idx] + v;
        } else if constexpr (EPI == 2){
          ((u16*)outp)[idx] = f2bf(gelu_f(v));
        } else {
          float* o = (float*)outp; o[idx] = o[idx] + v;
        }
      }
    }
  }
}

extern "C" void kernel_launch(void* const* d_in, const int* in_sizes, int n_in,
                              void* d_out, int out_size, void* d_ws, size_t ws_size,
                              hipStream_t stream){
  (void)in_sizes; (void)n_in; (void)out_size; (void)ws_size;
  const float* x    = (const float*)d_in[0];
  const float* ln1w = (const float*)d_in[1];
  const float* ln1b = (const float*)d_in[2];
  const float* qw   = (const float*)d_in[3];
  const float* qb   = (const float*)d_in[4];
  const float* kw   = (const float*)d_in[5];
  const float* kb   = (const float*)d_in[6];
  const float* vw   = (const float*)d_in[7];
  const float* vb   = (const float*)d_in[8];
  const float* ow   = (const float*)d_in[9];
  const float* ob   = (const float*)d_in[10];
  const float* ln2w = (const float*)d_in[11];
  const float* ln2b = (const float*)d_in[12];
  const float* fcw  = (const float*)d_in[13];
  const float* fcb  = (const float*)d_in[14];
  const float* pw   = (const float*)d_in[15];
  const float* pb   = (const float*)d_in[16];

  char* ws = (char*)d_ws;
  u16*   WQKV = (u16*)(ws + 0);              // [3072][1024] bf16 (q_w|k_w|v_w)
  u16*   WO   = (u16*)(ws + 6291456);        // [1024][1024]
  u16*   WFC  = (u16*)(ws + 8388608);        // [4096][1024]
  u16*   WPR  = (u16*)(ws + 16777216);       // [1024][4096]
  float* BQ   = (float*)(ws + 25165824);     // [3072]
  u16*   XN   = (u16*)(ws + 25178112);       // [16384][1024] bf16 (xn, reused for xn2)
  u16*   QKV  = (u16*)(ws + 58732544);       // [16384][3072] bf16
  u16*   ATT  = (u16*)(ws + 159395840);      // [16384][1024] bf16
  u16*   H    = QKV;                          // [16384][4096] bf16, reuses QKV+ATT region
  float* OUT  = (float*)d_out;               // x1 intermediate, then final output

  // weight casts (fp32 -> bf16)
  k_cast<<<512, 256, 0, stream>>>(qw, WQKV,           262144);
  k_cast<<<512, 256, 0, stream>>>(kw, WQKV + 1048576, 262144);
  k_cast<<<512, 256, 0, stream>>>(vw, WQKV + 2097152, 262144);
  k_cast<<<512, 256, 0, stream>>>(ow, WO,             262144);
  k_cast<<<1024, 256, 0, stream>>>(fcw, WFC,          1048576);
  k_cast<<<1024, 256, 0, stream>>>(pw,  WPR,          1048576);
  k_cat3<<<12, 256, 0, stream>>>(qb, kb, vb, BQ);

  // ln1 -> fused QKV gemm -> per-token attention -> O gemm (+x residual) -> OUT (x1)
  k_ln<<<16384, 256, 0, stream>>>(x, ln1w, ln1b, XN);
  k_gemm<0><<<64 * 12, 512, 0, stream>>>(XN, WQKV, BQ, nullptr, QKV, 3072, 1024, 12);
  k_attn<<<4096, 256, 0, stream>>>(QKV, ATT);
  k_gemm<1><<<64 * 4, 512, 0, stream>>>(ATT, WO, ob, x, OUT, 1024, 1024, 4);

  // ln2 -> FC gemm (+gelu) -> PROJ gemm (+x1 residual, in place on OUT)
  k_ln<<<16384, 256, 0, stream>>>(OUT, ln2w, ln2b, XN);
  k_gemm<2><<<64 * 16, 512, 0, stream>>>(XN, WFC, fcb, nullptr, H, 4096, 1024, 16);
  k_gemm<3><<<64 * 4, 512, 0, stream>>>(H, WPR, pb, nullptr, OUT, 1024, 4096, 4);
}